// Round 8
// baseline (899.693 us; speedup 1.0000x reference)
//
#include <hip/hip_runtime.h>
#include <math.h>

typedef unsigned short u16;
typedef unsigned int   u32;
typedef __attribute__((ext_vector_type(8))) short bf16x8;
typedef __attribute__((ext_vector_type(4))) float f32x4;

#define NROWS 32768   // BS*NAG
#define NAG 8
#define HID 256
#define INP 128
#define NACT 16
#define MESS 64
#define TRAJD 80
#define QD 64
#define HOFF 524288    // element offset of h inside d_out (q is 32768*16)

// ---------------- ws layout ----------------
#define PKO_FC1 0          // 4ks*3p*16nt  = 192 chunks * 512 u16
#define PKO_IH  98304      // 8*3*48 = 1152 chunks
#define PKO_HH  688128
#define PKO_TR  1277952    // 9*3*16 = 432
#define PKO_DEC 1499136    // 8*3*1  = 24
#define PKO_QKV 1511424    // 3*3*12 = 108
#define PKO_QIJ 1566720    // 10*3*1 = 30
#define PK_TOTAL 1582080   // u16  (= 791040 floats)
#define WS_CB   791040     // float offset: packed biases (2272 floats)
#define WS_FLAG 793312     // int flag: 1 = inputs fp32, 0 = bf16

// packed bias offsets within WS_CB
#define OB_FC1B 0
#define OB_BIH  256
#define OB_BHH  1024
#define OB_DECB 1792
#define OB_TRB  1808
#define OB_QIJB 2064
#define OB_QB   2080   // QB,KB,VB contiguous stride 64

__device__ __forceinline__ float bf2f(u16 v){ return __uint_as_float(((u32)v)<<16); }
__device__ __forceinline__ u16 f2bf(float f){
    u32 u = __float_as_uint(f);
    return (u16)((u + 0x7fffu + ((u>>16)&1u))>>16);   // RNE
}
__device__ __forceinline__ float sig_(float x){ return 1.0f/(1.0f+expf(-x)); }
__device__ __forceinline__ float ldin(const void* p, size_t i, int f32){
    return f32 ? ((const float*)p)[i] : bf2f(((const u16*)p)[i]);
}
// non-temporal scalar input read (streaming data)
__device__ __forceinline__ float ldin_nt(const void* p, size_t i, int f32){
    if (f32) return __builtin_nontemporal_load((const float*)p + i);
    return bf2f(__builtin_nontemporal_load((const u16*)p + i));
}
__device__ __forceinline__ void stout1(void* out, size_t i, float v, int f32){
    if (f32) ((float*)out)[i]=v; else ((u16*)out)[i]=f2bf(v);
}
__device__ __forceinline__ void stout1_nt(void* out, size_t i, float v, int f32){
    if (f32) __builtin_nontemporal_store(v, (float*)out + i);
    else     __builtin_nontemporal_store(f2bf(v), (u16*)out + i);
}
__device__ __forceinline__ void split3(float w, u16& s0, u16& s1, u16& s2){
    u16 a=f2bf(w); float r  = w - bf2f(a);
    u16 b=f2bf(r); float r2 = r - bf2f(b);
    s0=a; s1=b; s2=f2bf(r2);
}
__device__ __forceinline__ f32x4 splat4(float b){ f32x4 v = {b,b,b,b}; return v; }

#define MFMA(a,b,c) __builtin_amdgcn_mfma_f32_16x16x32_bf16((a),(b),(c),0,0,0)

// ---- LDS plane helpers, 32 rows (XOR bank swizzle: byte ^= (row&7)<<4) ----
// planes: stride 640 B/row (320 bf16 cols: 0..255 act, 256..263 action, 256..319 msg; 264..287 zero pad for trans K)
__device__ __forceinline__ bf16x8 lda_pl(const u16* P, int p, int row, int kbyte){
    const char* b = (const char*)P + ((p*32+row)*640) + (kbyte ^ ((row&7)<<4));
    return *(const bf16x8*)b;
}
__device__ __forceinline__ void stw_pl(u16* P, int p, int row, int col, u16 v){
    char* b = (char*)P + ((p*32+row)*640) + (((col*2)) ^ ((row&7)<<4));
    *(u16*)b = v;
}
__device__ __forceinline__ void split_store_pl(u16* P, int row, int col, float v){
    u16 a,b,c; split3(v,a,b,c);
    stw_pl(P,0,row,col,a); stw_pl(P,1,row,col,b); stw_pl(P,2,row,col,c);
}
// global A-fragment loads — non-temporal (streaming, zero reuse after this block)
__device__ __forceinline__ bf16x8 ldg_bf8(const void* p, size_t off){
    return __builtin_nontemporal_load((const bf16x8*)((const u16*)p + off));
}
__device__ __forceinline__ void ldg_f32_split(const void* p, size_t off, bf16x8& f0, bf16x8& f1, bf16x8& f2){
    const float* fp = (const float*)p + off;
    #pragma unroll
    for (int j=0;j<8;j++){
        float w = __builtin_nontemporal_load(fp + j);
        u16 a,b,c; split3(w,a,b,c);
        f0[j]=(short)a; f1[j]=(short)b; f2[j]=(short)c;
    }
}
// B-fragment chunk load (1 KB chunk, 16B/lane, perfectly coalesced) — CACHED (the L2-resident hot set)
#define BCH(base, NTv, ksv, pbv, ntv) \
    (*(const bf16x8*)((base) + ((((ksv)*3+(pbv))*(NTv) + (ntv))*512) + lane*8))

// ---------------- k_det: sniff input dtype ----------------
__global__ void k_det(const void* __restrict__ inp, int* __restrict__ flag){
    __shared__ int cnt;
    if (threadIdx.x==0) cnt=0;
    __syncthreads();
    int big=0;
    for (int i=threadIdx.x;i<128;i+=64){
        u32 w = ((const u32*)inp)[i];
        float g = bf2f((u16)w);
        if (!(fabsf(g) <= 1e4f)) big++;
    }
    if (big) atomicAdd(&cnt, big);
    __syncthreads();
    if (threadIdx.x==0) *flag = (cnt>=4) ? 1 : 0;
}

// ---------------- k0: pack weights into MFMA-fragment-linear bf16 planes ----------------
__device__ __forceinline__ void pack_tile(const void* W, int Kdim, int NT, u16* pk, int tau, int f32){
    int lane2 = tau & 63, c = tau >> 6;
    int nt = c % NT, ks = c / NT;
    int n  = nt*16 + (lane2 & 15);
    int kb = ks*32 + (lane2 >> 4)*8;
    u16 o0[8],o1[8],o2[8];
    #pragma unroll
    for (int j=0;j<8;j++){
        int k = kb + j;
        float w = (k < Kdim) ? ldin(W, (size_t)n*Kdim + k, f32) : 0.0f;
        split3(w, o0[j], o1[j], o2[j]);
    }
    size_t base = ((size_t)(ks*3+0)*NT + nt)*512 + lane2*8;
    size_t step = (size_t)NT*512;
    #pragma unroll
    for (int j=0;j<8;j++){
        pk[base+j]=o0[j]; pk[base+step+j]=o1[j]; pk[base+2*step+j]=o2[j];
    }
}

__global__ __launch_bounds__(256) void k0_prep(
    const void* fc1_w, const void* w_ih, const void* w_hh, const void* trans_w,
    const void* dec_w, const void* qij_w, const void* q_w, const void* k_w, const void* v_w,
    const void* fc1_b, const void* b_ih, const void* b_hh, const void* dec_b,
    const void* trans_b, const void* qij_b, const void* q_b, const void* k_b, const void* v_b,
    float* __restrict__ ws, const int* __restrict__ flagp)
{
    const int f32 = *flagp;
    u16* pk = (u16*)ws;
    int i = blockIdx.x*256 + threadIdx.x;
    if (i < 4096)        pack_tile(fc1_w,  128, 16, pk+PKO_FC1, i,        f32);
    else if (i < 28672)  pack_tile(w_ih,   256, 48, pk+PKO_IH,  i-4096,   f32);
    else if (i < 53248)  pack_tile(w_hh,   256, 48, pk+PKO_HH,  i-28672,  f32);
    else if (i < 62464)  pack_tile(trans_w,264, 16, pk+PKO_TR,  i-53248,  f32);
    else if (i < 62976)  pack_tile(dec_w,  256,  1, pk+PKO_DEC, i-62464,  f32);
    else if (i < 65280){ // qkv unified: N=192 (q 0..63, k 64..127, v 128..191), K=80 pad 96
        int tau = i - 62976;
        int lane2 = tau&63, c = tau>>6, nt = c%12, ks = c/12;
        int n = nt*16 + (lane2&15);
        const void* W = (n<64)? q_w : (n<128 ? k_w : v_w);
        int nl = n & 63;
        int kb = ks*32 + (lane2>>4)*8;
        u16 o0[8],o1[8],o2[8];
        #pragma unroll
        for (int j=0;j<8;j++){
            int k = kb + j;
            float w = (k < 80) ? ldin(W, (size_t)nl*80 + k, f32) : 0.0f;
            split3(w, o0[j], o1[j], o2[j]);
        }
        u16* dst = pk + PKO_QKV;
        size_t base = ((size_t)(ks*3+0)*12 + nt)*512 + lane2*8;
        size_t step = (size_t)12*512;
        #pragma unroll
        for (int j=0;j<8;j++){
            dst[base+j]=o0[j]; dst[base+step+j]=o1[j]; dst[base+2*step+j]=o2[j];
        }
    }
    else if (i < 65920)  pack_tile(qij_w,  320,  1, pk+PKO_QIJ, i-65280,  f32);
    else if (i < 68192){ // biases
        int i2 = i - 65920;
        float v;
        if      (i2<256)  v=ldin(fc1_b,i2,f32);
        else if (i2<1024) v=ldin(b_ih,i2-256,f32);
        else if (i2<1792) v=ldin(b_hh,i2-1024,f32);
        else if (i2<1808) v=ldin(dec_b,i2-1792,f32);
        else if (i2<2064) v=ldin(trans_b,i2-1808,f32);
        else if (i2<2080) v=ldin(qij_b,i2-2064,f32);
        else if (i2<2144) v=ldin(q_b,i2-2080,f32);
        else if (i2<2208) v=ldin(k_b,i2-2144,f32);
        else              v=ldin(v_b,i2-2208,f32);
        ws[WS_CB+i2]=v;
    }
}

// ---------------- k12: fully fused, r1 macro-shape: 1024 blocks x 512 thr x 32 rows ----------------
// 8 waves; wave w owns output cols nt0=w, nt1=w+8 and BOTH 16-row halves.
// LDS ~100KB -> exactly 1 block/CU = 2 waves/SIMD, REGARDLESS of VGPR count up to 256.
// r8 single-variable change: __launch_bounds__(512,1) instead of (512,2).
// Theory: the (512,2) bound capped arch-VGPRs at 128 (unified VGPR+AGPR file: 128+128=256
// = the 2-wave/SIMD budget) and the GRU/rollout phases spilled to scratch — the unexplained
// ~470 MB WRITE / ~760 MB FETCH (r4's 64-VGPR cap -> 2.9 GB WRITE is the same failure, amplified).
// Occupancy is LDS-pinned, so letting the allocator use more registers costs nothing.
template<int F32>
__global__ __launch_bounds__(512,1) void k12_fused(
    const void* __restrict__ inp, const void* __restrict__ oldh,
    const float* __restrict__ ws, void* __restrict__ dout, const int* __restrict__ flagp)
{
    if (*flagp != F32) return;                 // dual-instantiation dispatch
    constexpr int PBW = F32 ? 2 : 0;           // weight planes beyond 0 exist only in fp32 mode
    constexpr int PAG = F32 ? 2 : 0;           // raw-input planes beyond 0 likewise

    __shared__ __align__(16) u16   planes[3*32*320];   // act planes, 640B/row stride, 61440 B
    __shared__ __align__(16) float s_traj[32*100];     // fp32 traj, stride 100 (cols 80..99 zero)
    __shared__ __align__(16) float s_qkv[32*196];      // q|k|v fp32, stride 196
    __shared__ float s_att[256];                       // [row][m]

    const int t = threadIdx.x;
    const int wid = t>>6, lane = t&63, lr = lane&15, lk = lane>>4;
    const int nt0 = wid, nt1 = wid + 8;
    const int c0 = nt0*16+lr, c1 = nt1*16+lr;
    const int row0 = blockIdx.x*32;
    const u16* pk = (const u16*)ws;
    const float* cb = ws + WS_CB;
    const u16* pkf = pk + PKO_FC1;
    const u16* pki = pk + PKO_IH;
    const u16* pkh = pk + PKO_HH;
    const u16* pkt = pk + PKO_TR;
    const u16* pkd = pk + PKO_DEC;
    const u16* pkq = pk + PKO_QKV;
    const u16* pkj = pk + PKO_QIJ;

    // ---- P0: zero planes + traj (pad cols must read 0) ----
    for (int i=t;i<15360;i+=512) ((u32*)planes)[i]=0u;
    for (int i=t;i<3200;i+=512) s_traj[i]=0.f;
    __syncthreads();

    // ---- P1: fc1 + relu -> x planes ----
    {
        f32x4 acc[2][2];
        acc[0][0]=splat4(cb[OB_FC1B+c0]); acc[1][0]=acc[0][0];
        acc[0][1]=splat4(cb[OB_FC1B+c1]); acc[1][1]=acc[0][1];
        for (int ks=0;ks<4;ks++){
            bf16x8 a[2][3];
            if (F32){
                ldg_f32_split(inp,(size_t)(row0+lr)*INP + ks*32+lk*8,    a[0][0],a[0][1],a[0][2]);
                ldg_f32_split(inp,(size_t)(row0+16+lr)*INP + ks*32+lk*8, a[1][0],a[1][1],a[1][2]);
            } else {
                a[0][0]=ldg_bf8(inp,(size_t)(row0+lr)*INP + ks*32+lk*8);
                a[1][0]=ldg_bf8(inp,(size_t)(row0+16+lr)*INP + ks*32+lk*8);
            }
            #pragma unroll
            for (int pb=0;pb<=PBW;pb++){
                bf16x8 B0 = BCH(pkf,16,ks,pb,nt0);
                bf16x8 B1 = BCH(pkf,16,ks,pb,nt1);
                #pragma unroll
                for (int pa=0;pa<=((PAG<2-pb)?PAG:(2-pb));pa++){
                    acc[0][0]=MFMA(a[0][pa],B0,acc[0][0]); acc[0][1]=MFMA(a[0][pa],B1,acc[0][1]);
                    acc[1][0]=MFMA(a[1][pa],B0,acc[1][0]); acc[1][1]=MFMA(a[1][pa],B1,acc[1][1]);
                }
            }
        }
        #pragma unroll
        for (int m=0;m<2;m++)
        #pragma unroll
        for (int ni=0;ni<2;ni++)
        #pragma unroll
        for (int j=0;j<4;j++){
            float v = acc[m][ni][j]; v = v>0.f ? v : 0.f;
            split_store_pl(planes, m*16+lk*4+j, (ni?nt1:nt0)*16+lr, v);
        }
    }
    __syncthreads();

    // ---- P2: GRU ----
    float hreg[16];
    {
        f32x4 aR[2][2], aZ[2][2], aN[2][2], aH[2][2];
        #pragma unroll
        for (int m=0;m<2;m++)
        #pragma unroll
        for (int gi=0;gi<2;gi++){
            int c = (gi?nt1:nt0)*16 + lr;
            aR[m][gi]=splat4(cb[OB_BIH+c]     + cb[OB_BHH+c]);
            aZ[m][gi]=splat4(cb[OB_BIH+256+c] + cb[OB_BHH+256+c]);
            aN[m][gi]=splat4(cb[OB_BIH+512+c]);
            aH[m][gi]=splat4(cb[OB_BHH+512+c]);
        }
        // x @ Wih^T  (A = x planes in LDS)
        for (int ks=0;ks<8;ks++){
            #pragma unroll
            for (int pb=0;pb<=PBW;pb++){
                bf16x8 Br0=BCH(pki,48,ks,pb,   nt0), Br1=BCH(pki,48,ks,pb,   nt1);
                bf16x8 Bz0=BCH(pki,48,ks,pb,16+nt0), Bz1=BCH(pki,48,ks,pb,16+nt1);
                bf16x8 Bn0=BCH(pki,48,ks,pb,32+nt0), Bn1=BCH(pki,48,ks,pb,32+nt1);
                #pragma unroll
                for (int pa=0;pa<=2-pb;pa++){
                    bf16x8 a0 = lda_pl(planes, pa, lr,    ks*64+lk*16);
                    bf16x8 a1 = lda_pl(planes, pa, 16+lr, ks*64+lk*16);
                    aR[0][0]=MFMA(a0,Br0,aR[0][0]); aR[0][1]=MFMA(a0,Br1,aR[0][1]);
                    aR[1][0]=MFMA(a1,Br0,aR[1][0]); aR[1][1]=MFMA(a1,Br1,aR[1][1]);
                    aZ[0][0]=MFMA(a0,Bz0,aZ[0][0]); aZ[0][1]=MFMA(a0,Bz1,aZ[0][1]);
                    aZ[1][0]=MFMA(a1,Bz0,aZ[1][0]); aZ[1][1]=MFMA(a1,Bz1,aZ[1][1]);
                    aN[0][0]=MFMA(a0,Bn0,aN[0][0]); aN[0][1]=MFMA(a0,Bn1,aN[0][1]);
                    aN[1][0]=MFMA(a1,Bn0,aN[1][0]); aN[1][1]=MFMA(a1,Bn1,aN[1][1]);
                }
            }
        }
        // oldh @ Whh^T  (A = oldh from global, non-temporal)
        for (int ks=0;ks<8;ks++){
            bf16x8 a[2][3];
            if (F32){
                ldg_f32_split(oldh,(size_t)(row0+lr)*HID + ks*32+lk*8,    a[0][0],a[0][1],a[0][2]);
                ldg_f32_split(oldh,(size_t)(row0+16+lr)*HID + ks*32+lk*8, a[1][0],a[1][1],a[1][2]);
            } else {
                a[0][0]=ldg_bf8(oldh,(size_t)(row0+lr)*HID + ks*32+lk*8);
                a[1][0]=ldg_bf8(oldh,(size_t)(row0+16+lr)*HID + ks*32+lk*8);
            }
            #pragma unroll
            for (int pb=0;pb<=PBW;pb++){
                bf16x8 Br0=BCH(pkh,48,ks,pb,   nt0), Br1=BCH(pkh,48,ks,pb,   nt1);
                bf16x8 Bz0=BCH(pkh,48,ks,pb,16+nt0), Bz1=BCH(pkh,48,ks,pb,16+nt1);
                bf16x8 Bh0=BCH(pkh,48,ks,pb,32+nt0), Bh1=BCH(pkh,48,ks,pb,32+nt1);
                #pragma unroll
                for (int pa=0;pa<=((PAG<2-pb)?PAG:(2-pb));pa++){
                    aR[0][0]=MFMA(a[0][pa],Br0,aR[0][0]); aR[0][1]=MFMA(a[0][pa],Br1,aR[0][1]);
                    aR[1][0]=MFMA(a[1][pa],Br0,aR[1][0]); aR[1][1]=MFMA(a[1][pa],Br1,aR[1][1]);
                    aZ[0][0]=MFMA(a[0][pa],Bz0,aZ[0][0]); aZ[0][1]=MFMA(a[0][pa],Bz1,aZ[0][1]);
                    aZ[1][0]=MFMA(a[1][pa],Bz0,aZ[1][0]); aZ[1][1]=MFMA(a[1][pa],Bz1,aZ[1][1]);
                    aH[0][0]=MFMA(a[0][pa],Bh0,aH[0][0]); aH[0][1]=MFMA(a[0][pa],Bh1,aH[0][1]);
                    aH[1][0]=MFMA(a[1][pa],Bh0,aH[1][0]); aH[1][1]=MFMA(a[1][pa],Bh1,aH[1][1]);
                }
            }
        }
        // gates -> h (torch order r,z,n)
        #pragma unroll
        for (int m=0;m<2;m++)
        #pragma unroll
        for (int gi=0;gi<2;gi++)
        #pragma unroll
        for (int j=0;j<4;j++){
            int row = m*16 + lk*4 + j;
            int c   = (gi?nt1:nt0)*16 + lr;
            float r  = sig_(aR[m][gi][j]);
            float z  = sig_(aZ[m][gi][j]);
            float nv = tanhf(aN[m][gi][j] + r*aH[m][gi][j]);
            float ho = ldin_nt(oldh,(size_t)(row0+row)*HID + c, F32);
            float h  = (1.f-z)*nv + z*ho;
            hreg[m*8+gi*4+j] = h;
            if (F32)   // bf16 path writes h coalesced from plane0 below
                stout1_nt(dout,(size_t)HOFF + (size_t)(row0+row)*HID + c, h, F32);
        }
    }
    __syncthreads();   // all x-plane reads done
    #pragma unroll
    for (int m=0;m<2;m++)
    #pragma unroll
    for (int gi=0;gi<2;gi++)
    #pragma unroll
    for (int j=0;j<4;j++)
        split_store_pl(planes, m*16+lk*4+j, (gi?nt1:nt0)*16+lr, hreg[m*8+gi*4+j]);
    __syncthreads();   // h planes complete

    // coalesced h write (bf16 mode): plane0 == RNE bf16 of exact h; non-temporal full-line stores.
    if (!F32){
        #pragma unroll
        for (int c2=0;c2<2;c2++){
            int cid = t + c2*512;
            int row = cid>>5, c8 = cid&31;
            bf16x8 v = lda_pl(planes, 0, row, c8*16);
            __builtin_nontemporal_store(v, (bf16x8*)((u16*)dout + HOFF + (size_t)(row0+row)*HID + c8*8));
        }
    }

    // ---- P3: rollout: 5 x (dec -> argmax -> trans); dec redundant on all 8 waves ----
    #pragma unroll 1
    for (int s=0;s<5;s++){
        f32x4 d0[2], d1[2], d2[2];
        d0[0]=splat4(cb[OB_DECB+lr]); d0[1]=d0[0];
        d1[0]=splat4(0.f); d1[1]=d1[0]; d2[0]=d1[0]; d2[1]=d1[0];
        for (int ks=0;ks<8;ks++){
            #pragma unroll
            for (int pb=0;pb<=PBW;pb++){
                bf16x8 B = BCH(pkd,1,ks,pb,0);
                #pragma unroll
                for (int pa=0;pa<=2-pb;pa++){
                    bf16x8 a0 = lda_pl(planes, pa, lr,    ks*64+lk*16);
                    bf16x8 a1 = lda_pl(planes, pa, 16+lr, ks*64+lk*16);
                    if (pa==0){ d0[0]=MFMA(a0,B,d0[0]); d0[1]=MFMA(a1,B,d0[1]); }
                    else if (pa==1){ d1[0]=MFMA(a0,B,d1[0]); d1[1]=MFMA(a1,B,d1[1]); }
                    else { d2[0]=MFMA(a0,B,d2[0]); d2[1]=MFMA(a1,B,d2[1]); }
                }
            }
        }
        f32x4 q[2];
        #pragma unroll
        for (int m=0;m<2;m++)
        #pragma unroll
        for (int j=0;j<4;j++) q[m][j]=d0[m][j]+d1[m][j]+d2[m][j];
        if (wid==0){
            #pragma unroll
            for (int m=0;m<2;m++)
            #pragma unroll
            for (int j=0;j<4;j++) s_traj[(m*16+lk*4+j)*100 + s*16 + lr] = q[m][j];
        }
        if (s==4) break;
        // argmax per row (first-max tie rule); 16-lane butterfly, all lanes converge
        int act[2][4];
        #pragma unroll
        for (int m=0;m<2;m++)
        #pragma unroll
        for (int j=0;j<4;j++){
            float v = q[m][j]; int ai = lr;
            #pragma unroll
            for (int msk=1; msk<16; msk<<=1){
                float pv = __shfl_xor(v, msk);
                int   pi = __shfl_xor(ai, msk);
                if (pv>v || (pv==v && pi<ai)){ v=pv; ai=pi; }
            }
            act[m][j]=ai;
        }
        // scatter actions to plane0 cols 256..263 (disjoint from dec's K-range; no pre-barrier)
        if (wid==0 && lr<8){
            #pragma unroll
            for (int m=0;m<2;m++)
            #pragma unroll
            for (int j=0;j<4;j++){
                int R = m*16+lk*4+j;
                stw_pl(planes, 0, (R&~7)+lr, 256+(R&7), f2bf((float)act[m][j]));
            }
        }
        __syncthreads();   // actions visible; all dec reads done
        // trans: hc_next = [hc, ac] @ trans_w^T + b   (K=264 padded to 288)
        {
            f32x4 tc[2][2];
            tc[0][0]=splat4(cb[OB_TRB+c0]); tc[1][0]=tc[0][0];
            tc[0][1]=splat4(cb[OB_TRB+c1]); tc[1][1]=tc[0][1];
            for (int ks=0;ks<9;ks++){
                #pragma unroll
                for (int pb=0;pb<=PBW;pb++){
                    bf16x8 B0=BCH(pkt,16,ks,pb,nt0), B1=BCH(pkt,16,ks,pb,nt1);
                    #pragma unroll
                    for (int pa=0;pa<=2-pb;pa++){
                        bf16x8 a0 = lda_pl(planes,pa,lr,   ks*64+lk*16);
                        bf16x8 a1 = lda_pl(planes,pa,16+lr,ks*64+lk*16);
                        tc[0][0]=MFMA(a0,B0,tc[0][0]); tc[0][1]=MFMA(a0,B1,tc[0][1]);
                        tc[1][0]=MFMA(a1,B0,tc[1][0]); tc[1][1]=MFMA(a1,B1,tc[1][1]);
                    }
                }
            }
            __syncthreads();   // all plane reads done before overwrite
            #pragma unroll
            for (int m=0;m<2;m++)
            #pragma unroll
            for (int ni=0;ni<2;ni++)
            #pragma unroll
            for (int j=0;j<4;j++)
                split_store_pl(planes, m*16+lk*4+j, (ni?nt1:nt0)*16+lr, tc[m][ni][j]);
        }
        __syncthreads();
    }
    __syncthreads();   // s=4 dec plane reads + traj writes complete

    // ---- P4: fused agent attention + heads ----
    // restore exact h into planes cols 0..255 (hc_4 dead)
    #pragma unroll
    for (int m=0;m<2;m++)
    #pragma unroll
    for (int gi=0;gi<2;gi++)
    #pragma unroll
    for (int j=0;j<4;j++)
        split_store_pl(planes, m*16+lk*4+j, (gi?nt1:nt0)*16+lr, hreg[m*8+gi*4+j]);
    // q/k/v projections: [32 x 96pad] @ [96 x 192]; A split on the fly from fp32 traj
    if (wid<6){
        f32x4 acc[2][2];
        acc[0][0]=splat4(cb[OB_QB+2*wid*16+lr]);     acc[1][0]=acc[0][0];
        acc[0][1]=splat4(cb[OB_QB+(2*wid+1)*16+lr]); acc[1][1]=acc[0][1];
        for (int ks=0;ks<3;ks++){
            bf16x8 a[2][3];
            #pragma unroll
            for (int m=0;m<2;m++){
                const float* tp = s_traj + (m*16+lr)*100 + ks*32 + lk*8;
                #pragma unroll
                for (int e=0;e<8;e++){
                    u16 x0,x1,x2; split3(tp[e],x0,x1,x2);
                    a[m][0][e]=(short)x0; a[m][1][e]=(short)x1; a[m][2][e]=(short)x2;
                }
            }
            #pragma unroll
            for (int pb=0;pb<=PBW;pb++){
                bf16x8 B0 = BCH(pkq,12,ks,pb,2*wid);
                bf16x8 B1 = BCH(pkq,12,ks,pb,2*wid+1);
                #pragma unroll
                for (int pa=0;pa<=2-pb;pa++){
                    acc[0][0]=MFMA(a[0][pa],B0,acc[0][0]); acc[0][1]=MFMA(a[0][pa],B1,acc[0][1]);
                    acc[1][0]=MFMA(a[1][pa],B0,acc[1][0]); acc[1][1]=MFMA(a[1][pa],B1,acc[1][1]);
                }
            }
        }
        #pragma unroll
        for (int m=0;m<2;m++)
        #pragma unroll
        for (int j=0;j<4;j++){
            s_qkv[(m*16+lk*4+j)*196 + 2*wid*16+lr]     = acc[m][0][j];
            s_qkv[(m*16+lk*4+j)*196 + (2*wid+1)*16+lr] = acc[m][1][j];
        }
    }
    __syncthreads();
    if (t<256){   // scores / sqrt(MESS): 4 batches x 8 x 8
        int b=t>>6, n=(t>>3)&7, mm=t&7;
        const float* qv = s_qkv + (b*8+n)*196;
        const float* kv = s_qkv + (b*8+mm)*196 + 64;
        float a2=0.f;
        #pragma unroll
        for (int d2=0;d2<64;d2++) a2 += qv[d2]*kv[d2];
        s_att[t] = a2*0.125f;
    }
    __syncthreads();
    if (t<32){    // softmax over m
        float mx = s_att[t*8];
        #pragma unroll
        for (int j2=1;j2<8;j2++) mx = fmaxf(mx, s_att[t*8+j2]);
        float e[8]; float sum=0.f;
        #pragma unroll
        for (int j2=0;j2<8;j2++){ e[j2]=expf(s_att[t*8+j2]-mx); sum+=e[j2]; }
        float inv = 1.f/sum;
        #pragma unroll
        for (int j2=0;j2<8;j2++) s_att[t*8+j2] = e[j2]*inv;
    }
    __syncthreads();
    for (int o=t;o<2048;o+=512){   // message -> planes cols 256..319 (all 3 planes fresh)
        int row=o>>6, d2=o&63, b=row>>3;
        float a3=0.f;
        #pragma unroll
        for (int mm=0;mm<8;mm++) a3 += s_att[row*8+mm]*s_qkv[(b*8+mm)*196+128+d2];
        split_store_pl(planes, row, 256+d2, a3);
    }
    __syncthreads();
    // q = q_local + 0.5 * ([h,msg] @ qij_w^T + qij_b); redundant on all waves, wave0 stores
    {
        f32x4 e0[2], e1[2], e2[2];
        e0[0]=splat4(cb[OB_QIJB+lr]); e0[1]=e0[0];
        e1[0]=splat4(0.f); e1[1]=e1[0]; e2[0]=e1[0]; e2[1]=e1[0];
        for (int ks=0;ks<10;ks++){
            #pragma unroll
            for (int pb=0;pb<=PBW;pb++){
                bf16x8 B = BCH(pkj,1,ks,pb,0);
                #pragma unroll
                for (int pa=0;pa<=2-pb;pa++){
                    bf16x8 a0 = lda_pl(planes, pa, lr,    ks*64+lk*16);
                    bf16x8 a1 = lda_pl(planes, pa, 16+lr, ks*64+lk*16);
                    if (pa==0){ e0[0]=MFMA(a0,B,e0[0]); e0[1]=MFMA(a1,B,e0[1]); }
                    else if (pa==1){ e1[0]=MFMA(a0,B,e1[0]); e1[1]=MFMA(a1,B,e1[1]); }
                    else { e2[0]=MFMA(a0,B,e2[0]); e2[1]=MFMA(a1,B,e2[1]); }
                }
            }
        }
        if (wid==0){
            #pragma unroll
            for (int m=0;m<2;m++)
            #pragma unroll
            for (int j=0;j<4;j++){
                int row = m*16+lk*4+j;
                float ql = s_traj[row*100 + lr];   // exact q_local (step-0 traj)
                stout1_nt(dout,(size_t)(row0+row)*NACT + lr, ql + 0.5f*(e0[m][j]+e1[m][j]+e2[m][j]), F32);
            }
        }
    }
}

extern "C" void kernel_launch(void* const* d_in, const int* in_sizes, int n_in,
                              void* d_out, int out_size, void* d_ws, size_t ws_size,
                              hipStream_t stream)
{
    (void)in_sizes; (void)n_in; (void)out_size; (void)ws_size;
    const void* inputs = d_in[0];
    const void* oldh   = d_in[1];
    float* ws = (float*)d_ws;
    int* flagp = (int*)(ws + WS_FLAG);

    k_det<<<1,64,0,stream>>>(inputs, flagp);
    k0_prep<<<268,256,0,stream>>>(d_in[2],d_in[4],d_in[5],d_in[10],d_in[8],d_in[12],
                                  d_in[14],d_in[16],d_in[18],
                                  d_in[3],d_in[6],d_in[7],d_in[9],d_in[11],d_in[13],
                                  d_in[15],d_in[17],d_in[19],
                                  ws, flagp);
    k12_fused<0><<<1024,512,0,stream>>>(inputs, oldh, ws, d_out, flagp);
    k12_fused<1><<<1024,512,0,stream>>>(inputs, oldh, ws, d_out, flagp);
}

// Round 9
// 590.648 us; speedup vs baseline: 1.5232x; 1.5232x over previous
//
#include <hip/hip_runtime.h>
#include <math.h>

typedef unsigned short u16;
typedef unsigned int   u32;
typedef __attribute__((ext_vector_type(8))) short bf16x8;
typedef __attribute__((ext_vector_type(4))) float f32x4;

#define NROWS 32768   // BS*NAG
#define NAG 8
#define HID 256
#define INP 128
#define NACT 16
#define MESS 64
#define TRAJD 80
#define QD 64
#define HOFF 524288    // element offset of h inside d_out (q is 32768*16)

// ---------------- ws layout ----------------
#define PKO_FC1 0          // 4ks*3p*16nt  = 192 chunks * 512 u16
#define PKO_IH  98304      // 8*3*48 = 1152 chunks
#define PKO_HH  688128
#define PKO_TR  1277952    // 9*3*16 = 432
#define PKO_DEC 1499136    // 8*3*1  = 24
#define PKO_QKV 1511424    // 3*3*12 = 108
#define PKO_QIJ 1566720    // 10*3*1 = 30
#define PK_TOTAL 1582080   // u16  (= 791040 floats)
#define WS_CB   791040     // float offset: packed biases (2272 floats)
#define WS_FLAG 793312     // int flag: 1 = inputs fp32, 0 = bf16

// packed bias offsets within WS_CB
#define OB_FC1B 0
#define OB_BIH  256
#define OB_BHH  1024
#define OB_DECB 1792
#define OB_TRB  1808
#define OB_QIJB 2064
#define OB_QB   2080   // QB,KB,VB contiguous stride 64

__device__ __forceinline__ float bf2f(u16 v){ return __uint_as_float(((u32)v)<<16); }
__device__ __forceinline__ u16 f2bf(float f){
    u32 u = __float_as_uint(f);
    return (u16)((u + 0x7fffu + ((u>>16)&1u))>>16);   // RNE
}
__device__ __forceinline__ float sig_(float x){ return 1.0f/(1.0f+expf(-x)); }
__device__ __forceinline__ float ldin(const void* p, size_t i, int f32){
    return f32 ? ((const float*)p)[i] : bf2f(((const u16*)p)[i]);
}
__device__ __forceinline__ void stout1(void* out, size_t i, float v, int f32){
    if (f32) ((float*)out)[i]=v; else ((u16*)out)[i]=f2bf(v);
}
__device__ __forceinline__ void split3(float w, u16& s0, u16& s1, u16& s2){
    u16 a=f2bf(w); float r  = w - bf2f(a);
    u16 b=f2bf(r); float r2 = r - bf2f(b);
    s0=a; s1=b; s2=f2bf(r2);
}
__device__ __forceinline__ f32x4 splat4(float b){ f32x4 v = {b,b,b,b}; return v; }

#define MFMA(a,b,c) __builtin_amdgcn_mfma_f32_16x16x32_bf16((a),(b),(c),0,0,0)

// ---- LDS plane helpers, 32 rows (XOR bank swizzle: byte ^= (row&7)<<4) ----
// planes: stride 640 B/row (320 bf16 cols: 0..255 act, 256..263 action, 256..319 msg; 264..287 zero pad for trans K)
__device__ __forceinline__ bf16x8 lda_pl(const u16* P, int p, int row, int kbyte){
    const char* b = (const char*)P + ((p*32+row)*640) + (kbyte ^ ((row&7)<<4));
    return *(const bf16x8*)b;
}
__device__ __forceinline__ void stw_pl(u16* P, int p, int row, int col, u16 v){
    char* b = (char*)P + ((p*32+row)*640) + (((col*2)) ^ ((row&7)<<4));
    *(u16*)b = v;
}
__device__ __forceinline__ void split_store_pl(u16* P, int row, int col, float v){
    u16 a,b,c; split3(v,a,b,c);
    stw_pl(P,0,row,col,a); stw_pl(P,1,row,col,b); stw_pl(P,2,row,col,c);
}
// global A-fragment loads
__device__ __forceinline__ bf16x8 ldg_bf8(const void* p, size_t off){
    return *(const bf16x8*)((const u16*)p + off);
}
__device__ __forceinline__ void ldg_f32_split(const void* p, size_t off, bf16x8& f0, bf16x8& f1, bf16x8& f2){
    const float* fp = (const float*)p + off;
    #pragma unroll
    for (int j=0;j<8;j++){
        float w = fp[j];
        u16 a,b,c; split3(w,a,b,c);
        f0[j]=(short)a; f1[j]=(short)b; f2[j]=(short)c;
    }
}
// B-fragment chunk load (1 KB chunk, 16B/lane, perfectly coalesced)
#define BCH(base, NTv, ksv, pbv, ntv) \
    (*(const bf16x8*)((base) + ((((ksv)*3+(pbv))*(NTv) + (ntv))*512) + lane*8))

// ---------------- k_det: sniff input dtype ----------------
__global__ void k_det(const void* __restrict__ inp, int* __restrict__ flag){
    __shared__ int cnt;
    if (threadIdx.x==0) cnt=0;
    __syncthreads();
    int big=0;
    for (int i=threadIdx.x;i<128;i+=64){
        u32 w = ((const u32*)inp)[i];
        float g = bf2f((u16)w);
        if (!(fabsf(g) <= 1e4f)) big++;
    }
    if (big) atomicAdd(&cnt, big);
    __syncthreads();
    if (threadIdx.x==0) *flag = (cnt>=4) ? 1 : 0;
}

// ---------------- k0: pack weights into MFMA-fragment-linear bf16 planes ----------------
__device__ __forceinline__ void pack_tile(const void* W, int Kdim, int NT, u16* pk, int tau, int f32){
    int lane2 = tau & 63, c = tau >> 6;
    int nt = c % NT, ks = c / NT;
    int n  = nt*16 + (lane2 & 15);
    int kb = ks*32 + (lane2 >> 4)*8;
    u16 o0[8],o1[8],o2[8];
    #pragma unroll
    for (int j=0;j<8;j++){
        int k = kb + j;
        float w = (k < Kdim) ? ldin(W, (size_t)n*Kdim + k, f32) : 0.0f;
        split3(w, o0[j], o1[j], o2[j]);
    }
    size_t base = ((size_t)(ks*3+0)*NT + nt)*512 + lane2*8;
    size_t step = (size_t)NT*512;
    #pragma unroll
    for (int j=0;j<8;j++){
        pk[base+j]=o0[j]; pk[base+step+j]=o1[j]; pk[base+2*step+j]=o2[j];
    }
}

__global__ __launch_bounds__(256) void k0_prep(
    const void* fc1_w, const void* w_ih, const void* w_hh, const void* trans_w,
    const void* dec_w, const void* qij_w, const void* q_w, const void* k_w, const void* v_w,
    const void* fc1_b, const void* b_ih, const void* b_hh, const void* dec_b,
    const void* trans_b, const void* qij_b, const void* q_b, const void* k_b, const void* v_b,
    float* __restrict__ ws, const int* __restrict__ flagp)
{
    const int f32 = *flagp;
    u16* pk = (u16*)ws;
    int i = blockIdx.x*256 + threadIdx.x;
    if (i < 4096)        pack_tile(fc1_w,  128, 16, pk+PKO_FC1, i,        f32);
    else if (i < 28672)  pack_tile(w_ih,   256, 48, pk+PKO_IH,  i-4096,   f32);
    else if (i < 53248)  pack_tile(w_hh,   256, 48, pk+PKO_HH,  i-28672,  f32);
    else if (i < 62464)  pack_tile(trans_w,264, 16, pk+PKO_TR,  i-53248,  f32);
    else if (i < 62976)  pack_tile(dec_w,  256,  1, pk+PKO_DEC, i-62464,  f32);
    else if (i < 65280){ // qkv unified: N=192 (q 0..63, k 64..127, v 128..191), K=80 pad 96
        int tau = i - 62976;
        int lane2 = tau&63, c = tau>>6, nt = c%12, ks = c/12;
        int n = nt*16 + (lane2&15);
        const void* W = (n<64)? q_w : (n<128 ? k_w : v_w);
        int nl = n & 63;
        int kb = ks*32 + (lane2>>4)*8;
        u16 o0[8],o1[8],o2[8];
        #pragma unroll
        for (int j=0;j<8;j++){
            int k = kb + j;
            float w = (k < 80) ? ldin(W, (size_t)nl*80 + k, f32) : 0.0f;
            split3(w, o0[j], o1[j], o2[j]);
        }
        u16* dst = pk + PKO_QKV;
        size_t base = ((size_t)(ks*3+0)*12 + nt)*512 + lane2*8;
        size_t step = (size_t)12*512;
        #pragma unroll
        for (int j=0;j<8;j++){
            dst[base+j]=o0[j]; dst[base+step+j]=o1[j]; dst[base+2*step+j]=o2[j];
        }
    }
    else if (i < 65920)  pack_tile(qij_w,  320,  1, pk+PKO_QIJ, i-65280,  f32);
    else if (i < 68192){ // biases
        int i2 = i - 65920;
        float v;
        if      (i2<256)  v=ldin(fc1_b,i2,f32);
        else if (i2<1024) v=ldin(b_ih,i2-256,f32);
        else if (i2<1792) v=ldin(b_hh,i2-1024,f32);
        else if (i2<1808) v=ldin(dec_b,i2-1792,f32);
        else if (i2<2064) v=ldin(trans_b,i2-1808,f32);
        else if (i2<2080) v=ldin(qij_b,i2-2064,f32);
        else if (i2<2144) v=ldin(q_b,i2-2080,f32);
        else if (i2<2208) v=ldin(k_b,i2-2144,f32);
        else              v=ldin(v_b,i2-2208,f32);
        ws[WS_CB+i2]=v;
    }
}

// ---------------- k12: r1 macro-shape + zero-traffic structural wins only ----------------
// 1024 blocks x 512 thr x 32 rows; 8 waves; wave w owns cols nt0=w, nt1=w+8, both row halves.
// LDS ~100KB -> 1 block/CU. dec and qij stay on 2 waves ONLY (r6 lesson: redundant-wave
// B-chunk loads de-synchronize and miss L2: FETCH 124->795MB). Deltas vs r1 add NO global
// traffic: shfl-argmax (kills s_q/s_am + 2 barriers/step), fp32 s_traj (kills tplanes),
// coalesced bf16 h-write (kills scattered 2B stores).
template<int F32>
__global__ __launch_bounds__(512,2) void k12_fused(
    const void* __restrict__ inp, const void* __restrict__ oldh,
    const float* __restrict__ ws, void* __restrict__ dout, const int* __restrict__ flagp)
{
    if (*flagp != F32) return;                 // dual-instantiation dispatch
    constexpr int PBW = F32 ? 2 : 0;           // weight planes beyond 0 exist only in fp32 mode
    constexpr int PAG = F32 ? 2 : 0;           // raw-input planes beyond 0 likewise

    __shared__ __align__(16) u16   planes[3*32*320];   // act planes, 640B/row stride, 61440 B
    __shared__ __align__(16) float s_traj[32*100];     // fp32 traj, stride 100 (cols 80..99 zero)
    __shared__ __align__(16) float s_qkv[32*196];      // q|k|v fp32, stride 196
    __shared__ float s_att[256];                       // [row][m]

    const int t = threadIdx.x;
    const int wid = t>>6, lane = t&63, lr = lane&15, lk = lane>>4;
    const int nt0 = wid, nt1 = wid + 8;
    const int c0 = nt0*16+lr, c1 = nt1*16+lr;
    const int row0 = blockIdx.x*32;
    const u16* pk = (const u16*)ws;
    const float* cb = ws + WS_CB;
    const u16* pkf = pk + PKO_FC1;
    const u16* pki = pk + PKO_IH;
    const u16* pkh = pk + PKO_HH;
    const u16* pkt = pk + PKO_TR;
    const u16* pkd = pk + PKO_DEC;
    const u16* pkq = pk + PKO_QKV;
    const u16* pkj = pk + PKO_QIJ;

    // ---- P0: zero planes + traj (pad cols must read 0) ----
    for (int i=t;i<15360;i+=512) ((u32*)planes)[i]=0u;
    for (int i=t;i<3200;i+=512) s_traj[i]=0.f;
    __syncthreads();

    // ---- P1: fc1 + relu -> x planes ----
    {
        f32x4 acc[2][2];
        acc[0][0]=splat4(cb[OB_FC1B+c0]); acc[1][0]=acc[0][0];
        acc[0][1]=splat4(cb[OB_FC1B+c1]); acc[1][1]=acc[0][1];
        for (int ks=0;ks<4;ks++){
            bf16x8 a[2][3];
            if (F32){
                ldg_f32_split(inp,(size_t)(row0+lr)*INP + ks*32+lk*8,    a[0][0],a[0][1],a[0][2]);
                ldg_f32_split(inp,(size_t)(row0+16+lr)*INP + ks*32+lk*8, a[1][0],a[1][1],a[1][2]);
            } else {
                a[0][0]=ldg_bf8(inp,(size_t)(row0+lr)*INP + ks*32+lk*8);
                a[1][0]=ldg_bf8(inp,(size_t)(row0+16+lr)*INP + ks*32+lk*8);
            }
            #pragma unroll
            for (int pb=0;pb<=PBW;pb++){
                bf16x8 B0 = BCH(pkf,16,ks,pb,nt0);
                bf16x8 B1 = BCH(pkf,16,ks,pb,nt1);
                #pragma unroll
                for (int pa=0;pa<=((PAG<2-pb)?PAG:(2-pb));pa++){
                    acc[0][0]=MFMA(a[0][pa],B0,acc[0][0]); acc[0][1]=MFMA(a[0][pa],B1,acc[0][1]);
                    acc[1][0]=MFMA(a[1][pa],B0,acc[1][0]); acc[1][1]=MFMA(a[1][pa],B1,acc[1][1]);
                }
            }
        }
        #pragma unroll
        for (int m=0;m<2;m++)
        #pragma unroll
        for (int ni=0;ni<2;ni++)
        #pragma unroll
        for (int j=0;j<4;j++){
            float v = acc[m][ni][j]; v = v>0.f ? v : 0.f;
            split_store_pl(planes, m*16+lk*4+j, (ni?nt1:nt0)*16+lr, v);
        }
    }
    __syncthreads();

    // ---- P2: GRU ----
    float hreg[16];
    {
        f32x4 aR[2][2], aZ[2][2], aN[2][2], aH[2][2];
        #pragma unroll
        for (int m=0;m<2;m++)
        #pragma unroll
        for (int gi=0;gi<2;gi++){
            int c = (gi?nt1:nt0)*16 + lr;
            aR[m][gi]=splat4(cb[OB_BIH+c]     + cb[OB_BHH+c]);
            aZ[m][gi]=splat4(cb[OB_BIH+256+c] + cb[OB_BHH+256+c]);
            aN[m][gi]=splat4(cb[OB_BIH+512+c]);
            aH[m][gi]=splat4(cb[OB_BHH+512+c]);
        }
        // x @ Wih^T  (A = x planes in LDS)
        for (int ks=0;ks<8;ks++){
            #pragma unroll
            for (int pb=0;pb<=PBW;pb++){
                bf16x8 Br0=BCH(pki,48,ks,pb,   nt0), Br1=BCH(pki,48,ks,pb,   nt1);
                bf16x8 Bz0=BCH(pki,48,ks,pb,16+nt0), Bz1=BCH(pki,48,ks,pb,16+nt1);
                bf16x8 Bn0=BCH(pki,48,ks,pb,32+nt0), Bn1=BCH(pki,48,ks,pb,32+nt1);
                #pragma unroll
                for (int pa=0;pa<=2-pb;pa++){
                    bf16x8 a0 = lda_pl(planes, pa, lr,    ks*64+lk*16);
                    bf16x8 a1 = lda_pl(planes, pa, 16+lr, ks*64+lk*16);
                    aR[0][0]=MFMA(a0,Br0,aR[0][0]); aR[0][1]=MFMA(a0,Br1,aR[0][1]);
                    aR[1][0]=MFMA(a1,Br0,aR[1][0]); aR[1][1]=MFMA(a1,Br1,aR[1][1]);
                    aZ[0][0]=MFMA(a0,Bz0,aZ[0][0]); aZ[0][1]=MFMA(a0,Bz1,aZ[0][1]);
                    aZ[1][0]=MFMA(a1,Bz0,aZ[1][0]); aZ[1][1]=MFMA(a1,Bz1,aZ[1][1]);
                    aN[0][0]=MFMA(a0,Bn0,aN[0][0]); aN[0][1]=MFMA(a0,Bn1,aN[0][1]);
                    aN[1][0]=MFMA(a1,Bn0,aN[1][0]); aN[1][1]=MFMA(a1,Bn1,aN[1][1]);
                }
            }
        }
        // oldh @ Whh^T  (A = oldh from global)
        for (int ks=0;ks<8;ks++){
            bf16x8 a[2][3];
            if (F32){
                ldg_f32_split(oldh,(size_t)(row0+lr)*HID + ks*32+lk*8,    a[0][0],a[0][1],a[0][2]);
                ldg_f32_split(oldh,(size_t)(row0+16+lr)*HID + ks*32+lk*8, a[1][0],a[1][1],a[1][2]);
            } else {
                a[0][0]=ldg_bf8(oldh,(size_t)(row0+lr)*HID + ks*32+lk*8);
                a[1][0]=ldg_bf8(oldh,(size_t)(row0+16+lr)*HID + ks*32+lk*8);
            }
            #pragma unroll
            for (int pb=0;pb<=PBW;pb++){
                bf16x8 Br0=BCH(pkh,48,ks,pb,   nt0), Br1=BCH(pkh,48,ks,pb,   nt1);
                bf16x8 Bz0=BCH(pkh,48,ks,pb,16+nt0), Bz1=BCH(pkh,48,ks,pb,16+nt1);
                bf16x8 Bh0=BCH(pkh,48,ks,pb,32+nt0), Bh1=BCH(pkh,48,ks,pb,32+nt1);
                #pragma unroll
                for (int pa=0;pa<=((PAG<2-pb)?PAG:(2-pb));pa++){
                    aR[0][0]=MFMA(a[0][pa],Br0,aR[0][0]); aR[0][1]=MFMA(a[0][pa],Br1,aR[0][1]);
                    aR[1][0]=MFMA(a[1][pa],Br0,aR[1][0]); aR[1][1]=MFMA(a[1][pa],Br1,aR[1][1]);
                    aZ[0][0]=MFMA(a[0][pa],Bz0,aZ[0][0]); aZ[0][1]=MFMA(a[0][pa],Bz1,aZ[0][1]);
                    aZ[1][0]=MFMA(a[1][pa],Bz0,aZ[1][0]); aZ[1][1]=MFMA(a[1][pa],Bz1,aZ[1][1]);
                    aH[0][0]=MFMA(a[0][pa],Bh0,aH[0][0]); aH[0][1]=MFMA(a[0][pa],Bh1,aH[0][1]);
                    aH[1][0]=MFMA(a[1][pa],Bh0,aH[1][0]); aH[1][1]=MFMA(a[1][pa],Bh1,aH[1][1]);
                }
            }
        }
        // gates -> h (torch order r,z,n)
        #pragma unroll
        for (int m=0;m<2;m++)
        #pragma unroll
        for (int gi=0;gi<2;gi++)
        #pragma unroll
        for (int j=0;j<4;j++){
            int row = m*16 + lk*4 + j;
            int c   = (gi?nt1:nt0)*16 + lr;
            float r  = sig_(aR[m][gi][j]);
            float z  = sig_(aZ[m][gi][j]);
            float nv = tanhf(aN[m][gi][j] + r*aH[m][gi][j]);
            float ho = ldin(oldh,(size_t)(row0+row)*HID + c, F32);
            float h  = (1.f-z)*nv + z*ho;
            hreg[m*8+gi*4+j] = h;
            if (F32)   // bf16 path writes h coalesced from plane0 below
                stout1(dout,(size_t)HOFF + (size_t)(row0+row)*HID + c, h, F32);
        }
    }
    __syncthreads();   // all x-plane reads done
    #pragma unroll
    for (int m=0;m<2;m++)
    #pragma unroll
    for (int gi=0;gi<2;gi++)
    #pragma unroll
    for (int j=0;j<4;j++)
        split_store_pl(planes, m*16+lk*4+j, (gi?nt1:nt0)*16+lr, hreg[m*8+gi*4+j]);
    __syncthreads();   // h planes complete

    // coalesced h write (bf16 mode): plane0 == RNE bf16 of exact h; full-line 16B stores.
    if (!F32){
        #pragma unroll
        for (int c2=0;c2<2;c2++){
            int cid = t + c2*512;
            int row = cid>>5, c8 = cid&31;
            bf16x8 v = lda_pl(planes, 0, row, c8*16);
            *(bf16x8*)((u16*)dout + HOFF + (size_t)(row0+row)*HID + c8*8) = v;
        }
    }

    // ---- P3: rollout: 5 x (dec(2 waves) -> shfl argmax -> trans); 3 barriers/step ----
    #pragma unroll 1
    for (int s=0;s<5;s++){
        if (wid<2){
            const int m = wid;
            f32x4 d0 = splat4(cb[OB_DECB+lr]);
            f32x4 d1 = splat4(0.f), d2 = splat4(0.f);
            for (int ks=0;ks<8;ks++){
                #pragma unroll
                for (int pb=0;pb<=PBW;pb++){
                    bf16x8 B = BCH(pkd,1,ks,pb,0);
                    #pragma unroll
                    for (int pa=0;pa<=2-pb;pa++){
                        bf16x8 a = lda_pl(planes, pa, m*16+lr, ks*64+lk*16);
                        if (pa==0) d0=MFMA(a,B,d0); else if (pa==1) d1=MFMA(a,B,d1); else d2=MFMA(a,B,d2);
                    }
                }
            }
            f32x4 q;
            #pragma unroll
            for (int j=0;j<4;j++) q[j]=d0[j]+d1[j]+d2[j];
            #pragma unroll
            for (int j=0;j<4;j++) s_traj[(m*16+lk*4+j)*100 + s*16 + lr] = q[j];
            if (s<4){
                // argmax per row (first-max tie rule); 16-lane butterfly
                #pragma unroll
                for (int j=0;j<4;j++){
                    float v = q[j]; int ai = lr;
                    #pragma unroll
                    for (int msk=1; msk<16; msk<<=1){
                        float pv = __shfl_xor(v, msk);
                        int   pi = __shfl_xor(ai, msk);
                        if (pv>v || (pv==v && pi<ai)){ v=pv; ai=pi; }
                    }
                    // scatter action to plane0 cols 256..263 (disjoint from dec's K-range)
                    if (lr<8){
                        int R = m*16+lk*4+j;
                        stw_pl(planes, 0, (R&~7)+lr, 256+(R&7), f2bf((float)ai));
                    }
                }
            }
        }
        if (s==4) break;
        __syncthreads();   // actions visible; dec plane reads done (waves 2-7 waited here)
        // trans: hc_next = [hc, ac] @ trans_w^T + b   (K=264 padded to 288), all 8 waves
        {
            f32x4 tc[2][2];
            tc[0][0]=splat4(cb[OB_TRB+c0]); tc[1][0]=tc[0][0];
            tc[0][1]=splat4(cb[OB_TRB+c1]); tc[1][1]=tc[0][1];
            for (int ks=0;ks<9;ks++){
                #pragma unroll
                for (int pb=0;pb<=PBW;pb++){
                    bf16x8 B0=BCH(pkt,16,ks,pb,nt0), B1=BCH(pkt,16,ks,pb,nt1);
                    #pragma unroll
                    for (int pa=0;pa<=2-pb;pa++){
                        bf16x8 a0 = lda_pl(planes,pa,lr,   ks*64+lk*16);
                        bf16x8 a1 = lda_pl(planes,pa,16+lr,ks*64+lk*16);
                        tc[0][0]=MFMA(a0,B0,tc[0][0]); tc[0][1]=MFMA(a0,B1,tc[0][1]);
                        tc[1][0]=MFMA(a1,B0,tc[1][0]); tc[1][1]=MFMA(a1,B1,tc[1][1]);
                    }
                }
            }
            __syncthreads();   // all plane reads done before overwrite
            #pragma unroll
            for (int m=0;m<2;m++)
            #pragma unroll
            for (int ni=0;ni<2;ni++)
            #pragma unroll
            for (int j=0;j<4;j++)
                split_store_pl(planes, m*16+lk*4+j, (ni?nt1:nt0)*16+lr, tc[m][ni][j]);
        }
        __syncthreads();
    }
    __syncthreads();   // s=4 dec plane reads + traj writes complete

    // ---- P4: fused agent attention + heads ----
    // restore exact h into planes cols 0..255 (hc_4 dead)
    #pragma unroll
    for (int m=0;m<2;m++)
    #pragma unroll
    for (int gi=0;gi<2;gi++)
    #pragma unroll
    for (int j=0;j<4;j++)
        split_store_pl(planes, m*16+lk*4+j, (gi?nt1:nt0)*16+lr, hreg[m*8+gi*4+j]);
    // q/k/v projections: [32 x 96pad] @ [96 x 192]; A split on the fly from fp32 traj
    if (wid<6){
        f32x4 acc[2][2];
        acc[0][0]=splat4(cb[OB_QB+2*wid*16+lr]);     acc[1][0]=acc[0][0];
        acc[0][1]=splat4(cb[OB_QB+(2*wid+1)*16+lr]); acc[1][1]=acc[0][1];
        for (int ks=0;ks<3;ks++){
            bf16x8 a[2][3];
            #pragma unroll
            for (int m=0;m<2;m++){
                const float* tp = s_traj + (m*16+lr)*100 + ks*32 + lk*8;
                #pragma unroll
                for (int e=0;e<8;e++){
                    u16 x0,x1,x2; split3(tp[e],x0,x1,x2);
                    a[m][0][e]=(short)x0; a[m][1][e]=(short)x1; a[m][2][e]=(short)x2;
                }
            }
            #pragma unroll
            for (int pb=0;pb<=PBW;pb++){
                bf16x8 B0 = BCH(pkq,12,ks,pb,2*wid);
                bf16x8 B1 = BCH(pkq,12,ks,pb,2*wid+1);
                #pragma unroll
                for (int pa=0;pa<=2-pb;pa++){
                    acc[0][0]=MFMA(a[0][pa],B0,acc[0][0]); acc[0][1]=MFMA(a[0][pa],B1,acc[0][1]);
                    acc[1][0]=MFMA(a[1][pa],B0,acc[1][0]); acc[1][1]=MFMA(a[1][pa],B1,acc[1][1]);
                }
            }
        }
        #pragma unroll
        for (int m=0;m<2;m++)
        #pragma unroll
        for (int j=0;j<4;j++){
            s_qkv[(m*16+lk*4+j)*196 + 2*wid*16+lr]     = acc[m][0][j];
            s_qkv[(m*16+lk*4+j)*196 + (2*wid+1)*16+lr] = acc[m][1][j];
        }
    }
    __syncthreads();
    if (t<256){   // scores / sqrt(MESS): 4 batches x 8 x 8
        int b=t>>6, n=(t>>3)&7, mm=t&7;
        const float* qv = s_qkv + (b*8+n)*196;
        const float* kv = s_qkv + (b*8+mm)*196 + 64;
        float a2=0.f;
        #pragma unroll
        for (int d2=0;d2<64;d2++) a2 += qv[d2]*kv[d2];
        s_att[t] = a2*0.125f;
    }
    __syncthreads();
    if (t<32){    // softmax over m
        float mx = s_att[t*8];
        #pragma unroll
        for (int j2=1;j2<8;j2++) mx = fmaxf(mx, s_att[t*8+j2]);
        float e[8]; float sum=0.f;
        #pragma unroll
        for (int j2=0;j2<8;j2++){ e[j2]=expf(s_att[t*8+j2]-mx); sum+=e[j2]; }
        float inv = 1.f/sum;
        #pragma unroll
        for (int j2=0;j2<8;j2++) s_att[t*8+j2] = e[j2]*inv;
    }
    __syncthreads();
    for (int o=t;o<2048;o+=512){   // message -> planes cols 256..319 (all 3 planes fresh)
        int row=o>>6, d2=o&63, b=row>>3;
        float a3=0.f;
        #pragma unroll
        for (int mm=0;mm<8;mm++) a3 += s_att[row*8+mm]*s_qkv[(b*8+mm)*196+128+d2];
        split_store_pl(planes, row, 256+d2, a3);
    }
    __syncthreads();
    // q = q_local + 0.5 * ([h,msg] @ qij_w^T + qij_b); 2 waves, each owns its 16 rows
    if (wid<2){
        const int m = wid;
        f32x4 e0 = splat4(cb[OB_QIJB+lr]);
        f32x4 e1 = splat4(0.f), e2 = splat4(0.f);
        for (int ks=0;ks<10;ks++){
            #pragma unroll
            for (int pb=0;pb<=PBW;pb++){
                bf16x8 B = BCH(pkj,1,ks,pb,0);
                #pragma unroll
                for (int pa=0;pa<=2-pb;pa++){
                    bf16x8 a = lda_pl(planes, pa, m*16+lr, ks*64+lk*16);
                    if (pa==0) e0=MFMA(a,B,e0); else if (pa==1) e1=MFMA(a,B,e1); else e2=MFMA(a,B,e2);
                }
            }
        }
        #pragma unroll
        for (int j=0;j<4;j++){
            int row = m*16+lk*4+j;
            float ql = s_traj[row*100 + lr];   // exact q_local (step-0 traj)
            stout1(dout,(size_t)(row0+row)*NACT + lr, ql + 0.5f*(e0[j]+e1[j]+e2[j]), F32);
        }
    }
}

extern "C" void kernel_launch(void* const* d_in, const int* in_sizes, int n_in,
                              void* d_out, int out_size, void* d_ws, size_t ws_size,
                              hipStream_t stream)
{
    (void)in_sizes; (void)n_in; (void)out_size; (void)ws_size;
    const void* inputs = d_in[0];
    const void* oldh   = d_in[1];
    float* ws = (float*)d_ws;
    int* flagp = (int*)(ws + WS_FLAG);

    k_det<<<1,64,0,stream>>>(inputs, flagp);
    k0_prep<<<268,256,0,stream>>>(d_in[2],d_in[4],d_in[5],d_in[10],d_in[8],d_in[12],
                                  d_in[14],d_in[16],d_in[18],
                                  d_in[3],d_in[6],d_in[7],d_in[9],d_in[11],d_in[13],
                                  d_in[15],d_in[17],d_in[19],
                                  ws, flagp);
    k12_fused<0><<<1024,512,0,stream>>>(inputs, oldh, ws, d_out, flagp);
    k12_fused<1><<<1024,512,0,stream>>>(inputs, oldh, ws, d_out, flagp);
}